// Round 3
// baseline (109.646 us; speedup 1.0000x reference)
//
#include <hip/hip_runtime.h>
#include <math.h>

#define NB 32
#define KK 2
#define PP 256
#define NCLOUD 8192
#define NNODES 512   // K*P
#define NCOEF 163840 // B*K*P*COEF_D
#define CH 256                   // cloud points per surf block
#define NCHUNK (NCLOUD / CH)     // 32
#define NSURF (NB * NCHUNK)      // 1024
#define NBLK (64 + 64 + 64 + 1 + NSURF)  // 1217

__device__ inline float waveSum(float v) {
#pragma unroll
  for (int o = 32; o > 0; o >>= 1) v += __shfl_down(v, o);
  return v;
}
__device__ inline float waveMax(float v) {
#pragma unroll
  for (int o = 32; o > 0; o >>= 1) v = fmaxf(v, __shfl_down(v, o));
  return v;
}
__device__ inline float waveMin(float v) {
#pragma unroll
  for (int o = 32; o > 0; o >>= 1) v = fminf(v, __shfl_down(v, o));
  return v;
}
__device__ inline float smooth_l1(float d) {
  d = fabsf(d);
  return d < 0.1f ? 5.0f * d * d : d - 0.05f;
}

// Grid layout (longest roles first):
//   [0,64)    chamfer+sep per (b,k)
//   [64,128)  coverage per (b,k)
//   [128,192) regularizer
//   192       joint
//   [193,193+1024) surf: s = bid-193, b = s&31, chunk c = s>>5 (256 pts)
__global__ __launch_bounds__(256) void mega_kernel(
    const float* __restrict__ coefs,
    const float* __restrict__ preds,
    const float* __restrict__ nodes,
    const float* __restrict__ cloud,
    const int* __restrict__ cls,
    const float* __restrict__ pjl, const float* __restrict__ pja,
    const float* __restrict__ gjl, const float* __restrict__ gja,
    const float* __restrict__ gps,
    float* __restrict__ ws, unsigned int* __restrict__ minarr,
    float* __restrict__ out) {
  const int bid = blockIdx.x;
  const int t = threadIdx.x;
  const int wave = t >> 6, lane = t & 63;
  __shared__ float red[12][4];
  __shared__ int lastFlag;

  if (bid < 64) {
    // ---------------- chamfer + separation per (b,k) ----------------
    const int bk = bid;
    const float* pb = preds + (size_t)bk * PP * 3;
    const float* nbp = nodes + (size_t)bk * PP * 3;
    const float px = pb[t * 3 + 0], py = pb[t * 3 + 1], pz = pb[t * 3 + 2];
    const float nx = nbp[t * 3 + 0], ny = nbp[t * 3 + 1], nz = nbp[t * 3 + 2];
    const float s0 = gps[bk * 3 + 0], s1 = gps[bk * 3 + 1], s2 = gps[bk * 3 + 2];
    const float thr = sqrtf(s0 * s0 + s1 * s1 + s2 * s2) * 0.125f;
    float m1 = 1e30f, m2 = 1e30f, sep = 0.0f;
#pragma unroll 4
    for (int j = 0; j < PP; ++j) {
      // uniform (scalar) loads of point j
      const float ajx = nbp[j * 3 + 0], ajy = nbp[j * 3 + 1], ajz = nbp[j * 3 + 2];
      const float bjx = pb[j * 3 + 0], bjy = pb[j * 3 + 1], bjz = pb[j * 3 + 2];
      float dx = px - ajx, dy = py - ajy, dz = pz - ajz;
      m1 = fminf(m1, dx * dx + dy * dy + dz * dz);
      dx = nx - bjx; dy = ny - bjy; dz = nz - bjz;
      m2 = fminf(m2, dx * dx + dy * dy + dz * dz);
      dx = nx - ajx; dy = ny - ajy; dz = nz - ajz;
      const float d3 = sqrtf(dx * dx + dy * dy + dz * dz);
      const float rel = thr - d3;
      if (j != t && rel > 0.0f) sep += rel;
    }
    float chf = sqrtf(fmaxf(m1, 1e-12f)) + sqrtf(fmaxf(m2, 1e-12f));
    chf = waveSum(chf);
    sep = waveSum(sep);
    if (lane == 0) { red[0][wave] = chf; red[1][wave] = sep; }
    __syncthreads();
    if (t == 0) {
      atomicAdd(&ws[0], red[0][0] + red[0][1] + red[0][2] + red[0][3]);
      atomicAdd(&ws[1], red[1][0] + red[1][1] + red[1][2] + red[1][3]);
    }

  } else if (bid < 128) {
    // ---------------- coverage per (b,k) ----------------
    const int bk = bid - 64;
    const int b = bk >> 1;
    const int k = bk & 1;
    float pmax0 = -1e9f, pmax1 = -1e9f, pmax2 = -1e9f;
    float pmin0 = 1e9f, pmin1 = 1e9f, pmin2 = 1e9f;
    const float* cb = cloud + (size_t)b * NCLOUD * 3;
    const int* lb = cls + (size_t)b * NCLOUD;
    for (int i = t; i < NCLOUD; i += 256) {
      if (lb[i] == k) {
        const float x = cb[i * 3 + 0], y = cb[i * 3 + 1], z = cb[i * 3 + 2];
        pmax0 = fmaxf(pmax0, x); pmax1 = fmaxf(pmax1, y); pmax2 = fmaxf(pmax2, z);
        pmin0 = fminf(pmin0, x); pmin1 = fminf(pmin1, y); pmin2 = fminf(pmin2, z);
      }
    }
    const float* nb = nodes + (size_t)bk * PP * 3;
    const float kx = nb[t * 3 + 0], ky = nb[t * 3 + 1], kz = nb[t * 3 + 2];
    pmax0 = waveMax(pmax0); pmax1 = waveMax(pmax1); pmax2 = waveMax(pmax2);
    pmin0 = waveMin(pmin0); pmin1 = waveMin(pmin1); pmin2 = waveMin(pmin2);
    float kmax0 = waveMax(kx), kmax1 = waveMax(ky), kmax2 = waveMax(kz);
    float kmin0 = waveMin(kx), kmin1 = waveMin(ky), kmin2 = waveMin(kz);
    if (lane == 0) {
      red[0][wave] = pmax0; red[1][wave] = pmax1; red[2][wave] = pmax2;
      red[3][wave] = pmin0; red[4][wave] = pmin1; red[5][wave] = pmin2;
      red[6][wave] = kmax0; red[7][wave] = kmax1; red[8][wave] = kmax2;
      red[9][wave] = kmin0; red[10][wave] = kmin1; red[11][wave] = kmin2;
    }
    __syncthreads();
    if (t == 0) {
      float v[12];
#pragma unroll
      for (int q = 0; q < 12; ++q) {
        if (q < 3 || (q >= 6 && q < 9))
          v[q] = fmaxf(fmaxf(red[q][0], red[q][1]), fmaxf(red[q][2], red[q][3]));
        else
          v[q] = fminf(fminf(red[q][0], red[q][1]), fminf(red[q][2], red[q][3]));
      }
      float s = 0.0f;
#pragma unroll
      for (int c2 = 0; c2 < 3; ++c2)
        s += 0.5f * (smooth_l1(v[6 + c2] - v[0 + c2]) + smooth_l1(v[9 + c2] - v[3 + c2]));
      atomicAdd(&ws[3], s);
    }

  } else if (bid < 192) {
    // ---------------- regularizer ----------------
    const int r = bid - 128;
    const float4* c4 = (const float4*)coefs;
    float v = 0.0f;
    for (int i = r * 256 + t; i < NCOEF / 4; i += 64 * 256) {
      const float4 q = c4[i];
      v += q.x * q.x + q.y * q.y + q.z * q.z + q.w * q.w;
    }
    v = waveSum(v);
    if (lane == 0) red[0][wave] = v;
    __syncthreads();
    if (t == 0)
      atomicAdd(&ws[6], red[0][0] + red[0][1] + red[0][2] + red[0][3]);

  } else if (bid == 192) {
    // ---------------- joint ----------------
    float cosv = 0.0f, locv = 0.0f;
    if (t < NB) {
      const float axj = pja[t * 3 + 0], ayj = pja[t * 3 + 1], azj = pja[t * 3 + 2];
      const float gx = gja[t * 3 + 0], gy = gja[t * 3 + 1], gz = gja[t * 3 + 2];
      const float dot = axj * gx + ayj * gy + azj * gz;
      const float na = sqrtf(axj * axj + ayj * ayj + azj * azj);
      const float nbn = sqrtf(gx * gx + gy * gy + gz * gz);
      cosv = dot / fmaxf(na * nbn, 1e-8f);
      const float ux = gx / nbn, uy = gy / nbn, uz = gz / nbn;
      const float px = gjl[t * 3 + 0], py = gjl[t * 3 + 1], pz = gjl[t * 3 + 2];
      const float qx = px + ux, qy = py + uy, qz = pz + uz;
      const float rx = pjl[t * 3 + 0], ry = pjl[t * 3 + 1], rz = pjl[t * 3 + 2];
      const float xx = px - qx, xy = py - qy, xz = pz - qz;
      const float tnum = (rx - qx) * xx + (ry - qy) * xy + (rz - qz) * xz;
      const float tden = xx * xx + xy * xy + xz * xz;
      const float tv = tnum / tden;
      const float vx = tv * xx + (qx - rx);
      const float vy = tv * xy + (qy - ry);
      const float vz = tv * xz + (qz - rz);
      locv = sqrtf(vx * vx + vy * vy + vz * vz);
    }
    cosv = waveSum(cosv);
    locv = waveSum(locv);
    if (t == 0) { atomicAdd(&ws[4], cosv); atomicAdd(&ws[5], locv); }

  } else {
    // ---------------- surface loss partial: (b, 256-pt chunk) ----------------
    const int s = bid - 193;
    const int b = s & 31;
    const int c = s >> 5;
    const float* cb = cloud + ((size_t)b * NCLOUD + (size_t)c * CH) * 3;
    const float* nb = nodes + (size_t)b * NNODES * 3;
    const float ax = nb[t * 3 + 0], ay = nb[t * 3 + 1], az = nb[t * 3 + 2];
    const float bx = nb[(t + 256) * 3 + 0], by = nb[(t + 256) * 3 + 1],
                bz = nb[(t + 256) * 3 + 2];
    const float aa = ax * ax + ay * ay + az * az;
    const float bb = bx * bx + by * by + bz * bz;
    float m0 = 1e30f, m1 = 1e30f;  // min of g = 0.5|q|^2 - n.q
#pragma unroll 4
    for (int j = 0; j < CH; ++j) {
      // uniform (scalar) loads of cloud point j
      const float qx = cb[j * 3 + 0], qy = cb[j * 3 + 1], qz = cb[j * 3 + 2];
      const float hq = 0.5f * (qx * qx + qy * qy + qz * qz);
      float g = hq - (ax * qx + ay * qy + az * qz);
      m0 = fminf(m0, g);
      g = hq - (bx * qx + by * qy + bz * qz);
      m1 = fminf(m1, g);
    }
    // d^2 partial per node; clamp at 0 so uint-compare == float-compare
    const unsigned int u0 = __float_as_uint(fmaxf(2.0f * m0 + aa, 0.0f));
    const unsigned int u1 = __float_as_uint(fmaxf(2.0f * m1 + bb, 0.0f));
    // pre-filter: stale read >= current value (monotone decreasing) -> safe skip
    unsigned int* p0 = &minarr[b * NNODES + t];
    unsigned int* p1 = &minarr[b * NNODES + 256 + t];
    if (*p0 > u0) atomicMin(p0, u0);
    if (*p1 > u1) atomicMin(p1, u1);
  }

  // ---------------- ticket: last block reduces + combines ----------------
  __threadfence();
  __syncthreads();
  if (t == 0)
    lastFlag = (atomicAdd((unsigned int*)(ws + 7), 1u) == (unsigned int)(NBLK - 1));
  __syncthreads();
  if (lastFlag) {
    __threadfence();  // acquire: invalidate caches before reading others' results
    float ssum = 0.0f;
    const uint4* m4 = (const uint4*)minarr;
    for (int i = t; i < NB * NNODES / 4; i += 256) {
      const uint4 v = m4[i];
      ssum += sqrtf(fmaxf(__uint_as_float(v.x), 1e-12f));
      ssum += sqrtf(fmaxf(__uint_as_float(v.y), 1e-12f));
      ssum += sqrtf(fmaxf(__uint_as_float(v.z), 1e-12f));
      ssum += sqrtf(fmaxf(__uint_as_float(v.w), 1e-12f));
    }
    ssum = waveSum(ssum);
    __syncthreads();
    if (lane == 0) red[0][wave] = ssum;
    __syncthreads();
    if (t == 0) {
      const float surf_sum = red[0][0] + red[0][1] + red[0][2] + red[0][3];
      const float chf = ws[0] / (float)(KK * NB * PP);
      const float sep = ws[1] / (float)(NB * KK * PP * (PP - 1));
      const float surf = surf_sum / (float)(NB * NNODES);
      const float cov = ws[3] / (float)(NB * KK * 3);
      const float axis = 1.0f - ws[4] / (float)NB;
      const float loc = ws[5] / (float)NB;
      const float reg = ws[6] / (float)NCOEF;
      out[0] = chf + cov + surf * 5.0f + (loc + 0.5f * axis) + reg * 0.01f + sep * 2.0f;
    }
  }
}

extern "C" void kernel_launch(void* const* d_in, const int* in_sizes, int n_in,
                              void* d_out, int out_size, void* d_ws, size_t ws_size,
                              hipStream_t stream) {
  const float* coefs = (const float*)d_in[0];
  const float* preds = (const float*)d_in[1];
  const float* nodes = (const float*)d_in[2];
  const float* cloud = (const float*)d_in[3];
  const int* cls = (const int*)d_in[4];
  const float* pjl = (const float*)d_in[5];
  const float* pja = (const float*)d_in[6];
  const float* gjl = (const float*)d_in[7];
  const float* gja = (const float*)d_in[8];
  const float* gps = (const float*)d_in[9];
  float* out = (float*)d_out;
  float* ws = (float*)d_ws;
  unsigned int* minarr = (unsigned int*)(ws + 8);

  hipMemsetAsync(ws, 0, 8 * sizeof(float), stream);
  hipMemsetAsync(minarr, 0xFF, NB * NNODES * sizeof(unsigned int), stream);
  mega_kernel<<<NBLK, 256, 0, stream>>>(coefs, preds, nodes, cloud, cls,
                                        pjl, pja, gjl, gja, gps, ws, minarr, out);
}

// Round 4
// 105.026 us; speedup vs baseline: 1.0440x; 1.0440x over previous
//
#include <hip/hip_runtime.h>
#include <math.h>

#define NB 32
#define KK 2
#define PP 256
#define NCLOUD 8192
#define NNODES 512   // K*P
#define NCOEF 163840 // B*K*P*COEF_D
#define CH 256                    // cloud points per surf block
#define NCHUNK (NCLOUD / CH)      // 32
#define NSURF (NB * NCHUNK)       // 1024
#define SURF0 193
#define NBLK (SURF0 + NSURF)      // 1217

__device__ inline float waveSum(float v) {
#pragma unroll
  for (int o = 32; o > 0; o >>= 1) v += __shfl_down(v, o);
  return v;
}
__device__ inline float waveMax(float v) {
#pragma unroll
  for (int o = 32; o > 0; o >>= 1) v = fmaxf(v, __shfl_down(v, o));
  return v;
}
__device__ inline float waveMin(float v) {
#pragma unroll
  for (int o = 32; o > 0; o >>= 1) v = fminf(v, __shfl_down(v, o));
  return v;
}
__device__ inline float smooth_l1(float d) {
  d = fabsf(d);
  return d < 0.1f ? 5.0f * d * d : d - 0.05f;
}

// Grid layout:
//   [0,64)    chamfer+sep per (b,k)
//   [64,128)  coverage per (b,k)
//   [128,192) regularizer
//   192       joint
//   [193,193+1024) surf: s = bid-193, b = s&31, chunk c = s>>5 (256 pts)
__global__ __launch_bounds__(256) void mega_kernel(
    const float* __restrict__ coefs,
    const float* __restrict__ preds,
    const float* __restrict__ nodes,
    const float* __restrict__ cloud,
    const int* __restrict__ cls,
    const float* __restrict__ pjl, const float* __restrict__ pja,
    const float* __restrict__ gjl, const float* __restrict__ gja,
    const float* __restrict__ gps,
    float* __restrict__ ws, unsigned int* __restrict__ minarr,
    float* __restrict__ out) {
  const int bid = blockIdx.x;
  const int t = threadIdx.x;
  const int wave = t >> 6, lane = t & 63;
  __shared__ float4 sh4[2 * PP];   // 8 KB, role-dependent use
  __shared__ float red[12][4];
  __shared__ int lastFlag;

  if (bid < 64) {
    // ---------------- chamfer + separation per (b,k) ----------------
    const int bk = bid;
    const float* pb = preds + (size_t)bk * PP * 3;
    const float* nbp = nodes + (size_t)bk * PP * 3;
    {
      const float x = pb[3 * t], y = pb[3 * t + 1], z = pb[3 * t + 2];
      sh4[t] = make_float4(x, y, z, x * x + y * y + z * z);
      const float u = nbp[3 * t], v = nbp[3 * t + 1], w = nbp[3 * t + 2];
      sh4[PP + t] = make_float4(u, v, w, u * u + v * v + w * w);
    }
    __syncthreads();
    const float4 pt = sh4[t];        // pred_t, .w = |p|^2
    const float4 nt = sh4[PP + t];   // node_t, .w = |n|^2
    const float s0 = gps[bk * 3 + 0], s1 = gps[bk * 3 + 1], s2 = gps[bk * 3 + 2];
    const float thr = sqrtf(s0 * s0 + s1 * s1 + s2 * s2) * 0.125f;
    float g1 = 1e30f, g2 = 1e30f, sep = 0.0f;
#pragma unroll 2
    for (int j = 0; j < PP; ++j) {
      const float4 pj = sh4[j];
      const float4 nj = sh4[PP + j];
      // fwd: dist(pred_t, node_j): d2 = pt.w + (nj.w - 2 pt.nj)
      float dot = fmaf(pt.x, nj.x, fmaf(pt.y, nj.y, pt.z * nj.z));
      g1 = fminf(g1, fmaf(-2.0f, dot, nj.w));
      // bwd: dist(node_t, pred_j)
      dot = fmaf(nt.x, pj.x, fmaf(nt.y, pj.y, nt.z * pj.z));
      g2 = fminf(g2, fmaf(-2.0f, dot, pj.w));
      // sep: dist(node_t, node_j)
      dot = fmaf(nt.x, nj.x, fmaf(nt.y, nj.y, nt.z * nj.z));
      const float d2 = fmaf(-2.0f, dot, nt.w + nj.w);
      const float d = sqrtf(fmaxf(d2, 0.0f));
      if (j != t) sep += fmaxf(thr - d, 0.0f);
    }
    float chf = sqrtf(fmaxf(pt.w + g1, 1e-12f)) + sqrtf(fmaxf(nt.w + g2, 1e-12f));
    chf = waveSum(chf);
    sep = waveSum(sep);
    if (lane == 0) { red[0][wave] = chf; red[1][wave] = sep; }
    __syncthreads();
    if (t == 0) {
      atomicAdd(&ws[0], red[0][0] + red[0][1] + red[0][2] + red[0][3]);
      atomicAdd(&ws[1], red[1][0] + red[1][1] + red[1][2] + red[1][3]);
    }

  } else if (bid < 128) {
    // ---------------- coverage per (b,k) ----------------
    const int bk = bid - 64;
    const int b = bk >> 1;
    const int k = bk & 1;
    float pmax0 = -1e9f, pmax1 = -1e9f, pmax2 = -1e9f;
    float pmin0 = 1e9f, pmin1 = 1e9f, pmin2 = 1e9f;
    const float* cb = cloud + (size_t)b * NCLOUD * 3;
    const int* lb = cls + (size_t)b * NCLOUD;
    for (int i = t; i < NCLOUD; i += 256) {
      if (lb[i] == k) {
        const float x = cb[i * 3 + 0], y = cb[i * 3 + 1], z = cb[i * 3 + 2];
        pmax0 = fmaxf(pmax0, x); pmax1 = fmaxf(pmax1, y); pmax2 = fmaxf(pmax2, z);
        pmin0 = fminf(pmin0, x); pmin1 = fminf(pmin1, y); pmin2 = fminf(pmin2, z);
      }
    }
    const float* nb = nodes + (size_t)bk * PP * 3;
    const float kx = nb[t * 3 + 0], ky = nb[t * 3 + 1], kz = nb[t * 3 + 2];
    pmax0 = waveMax(pmax0); pmax1 = waveMax(pmax1); pmax2 = waveMax(pmax2);
    pmin0 = waveMin(pmin0); pmin1 = waveMin(pmin1); pmin2 = waveMin(pmin2);
    float kmax0 = waveMax(kx), kmax1 = waveMax(ky), kmax2 = waveMax(kz);
    float kmin0 = waveMin(kx), kmin1 = waveMin(ky), kmin2 = waveMin(kz);
    if (lane == 0) {
      red[0][wave] = pmax0; red[1][wave] = pmax1; red[2][wave] = pmax2;
      red[3][wave] = pmin0; red[4][wave] = pmin1; red[5][wave] = pmin2;
      red[6][wave] = kmax0; red[7][wave] = kmax1; red[8][wave] = kmax2;
      red[9][wave] = kmin0; red[10][wave] = kmin1; red[11][wave] = kmin2;
    }
    __syncthreads();
    if (t == 0) {
      float v[12];
#pragma unroll
      for (int q = 0; q < 12; ++q) {
        if (q < 3 || (q >= 6 && q < 9))
          v[q] = fmaxf(fmaxf(red[q][0], red[q][1]), fmaxf(red[q][2], red[q][3]));
        else
          v[q] = fminf(fminf(red[q][0], red[q][1]), fminf(red[q][2], red[q][3]));
      }
      float s = 0.0f;
#pragma unroll
      for (int c2 = 0; c2 < 3; ++c2)
        s += 0.5f * (smooth_l1(v[6 + c2] - v[0 + c2]) + smooth_l1(v[9 + c2] - v[3 + c2]));
      atomicAdd(&ws[3], s);
    }

  } else if (bid < 192) {
    // ---------------- regularizer ----------------
    const int r = bid - 128;
    const float4* c4 = (const float4*)coefs;
    float v = 0.0f;
    for (int i = r * 256 + t; i < NCOEF / 4; i += 64 * 256) {
      const float4 q = c4[i];
      v += q.x * q.x + q.y * q.y + q.z * q.z + q.w * q.w;
    }
    v = waveSum(v);
    if (lane == 0) red[0][wave] = v;
    __syncthreads();
    if (t == 0)
      atomicAdd(&ws[6], red[0][0] + red[0][1] + red[0][2] + red[0][3]);

  } else if (bid == 192) {
    // ---------------- joint ----------------
    float cosv = 0.0f, locv = 0.0f;
    if (t < NB) {
      const float axj = pja[t * 3 + 0], ayj = pja[t * 3 + 1], azj = pja[t * 3 + 2];
      const float gx = gja[t * 3 + 0], gy = gja[t * 3 + 1], gz = gja[t * 3 + 2];
      const float dot = axj * gx + ayj * gy + azj * gz;
      const float na = sqrtf(axj * axj + ayj * ayj + azj * azj);
      const float nbn = sqrtf(gx * gx + gy * gy + gz * gz);
      cosv = dot / fmaxf(na * nbn, 1e-8f);
      const float ux = gx / nbn, uy = gy / nbn, uz = gz / nbn;
      const float px = gjl[t * 3 + 0], py = gjl[t * 3 + 1], pz = gjl[t * 3 + 2];
      const float qx = px + ux, qy = py + uy, qz = pz + uz;
      const float rx = pjl[t * 3 + 0], ry = pjl[t * 3 + 1], rz = pjl[t * 3 + 2];
      const float xx = px - qx, xy = py - qy, xz = pz - qz;
      const float tnum = (rx - qx) * xx + (ry - qy) * xy + (rz - qz) * xz;
      const float tden = xx * xx + xy * xy + xz * xz;
      const float tv = tnum / tden;
      const float vx = tv * xx + (qx - rx);
      const float vy = tv * xy + (qy - ry);
      const float vz = tv * xz + (qz - rz);
      locv = sqrtf(vx * vx + vy * vy + vz * vz);
    }
    cosv = waveSum(cosv);
    locv = waveSum(locv);
    if (t == 0) { atomicAdd(&ws[4], cosv); atomicAdd(&ws[5], locv); }

  } else {
    // ---------------- surface loss partial: (b, 256-pt chunk) ----------------
    const int s = bid - SURF0;
    const int b = s & 31;
    const int c = s >> 5;
    const float* cb = cloud + ((size_t)b * NCLOUD + (size_t)c * CH) * 3;
    {
      const float qx = cb[3 * t], qy = cb[3 * t + 1], qz = cb[3 * t + 2];
      sh4[t] = make_float4(qx, qy, qz, 0.5f * (qx * qx + qy * qy + qz * qz));
    }
    __syncthreads();
    const float* nb = nodes + (size_t)b * NNODES * 3;
    const float ax = nb[t * 3 + 0], ay = nb[t * 3 + 1], az = nb[t * 3 + 2];
    const float bx = nb[(t + 256) * 3 + 0], by = nb[(t + 256) * 3 + 1],
                bz = nb[(t + 256) * 3 + 2];
    const float aa = ax * ax + ay * ay + az * az;
    const float bb = bx * bx + by * by + bz * bz;
    // accumulate min of g = 0.5|q|^2 - n.q ; even/odd accumulators for ILP
    float m0a = 1e30f, m0b = 1e30f, m1a = 1e30f, m1b = 1e30f;
#pragma unroll 4
    for (int j = 0; j < CH; j += 2) {
      const float4 q0 = sh4[j];
      const float4 q1 = sh4[j + 1];
      m0a = fminf(m0a, fmaf(-ax, q0.x, fmaf(-ay, q0.y, fmaf(-az, q0.z, q0.w))));
      m1a = fminf(m1a, fmaf(-bx, q0.x, fmaf(-by, q0.y, fmaf(-bz, q0.z, q0.w))));
      m0b = fminf(m0b, fmaf(-ax, q1.x, fmaf(-ay, q1.y, fmaf(-az, q1.z, q1.w))));
      m1b = fminf(m1b, fmaf(-bx, q1.x, fmaf(-by, q1.y, fmaf(-bz, q1.z, q1.w))));
    }
    const float m0 = fminf(m0a, m0b), m1 = fminf(m1a, m1b);
    const unsigned int u0 = __float_as_uint(fmaxf(2.0f * m0 + aa, 0.0f));
    const unsigned int u1 = __float_as_uint(fmaxf(2.0f * m1 + bb, 0.0f));
    unsigned int* p0 = &minarr[b * NNODES + t];
    unsigned int* p1 = &minarr[b * NNODES + 256 + t];
    if (*p0 > u0) atomicMin(p0, u0);   // stale read >= current: skip is safe
    if (*p1 > u1) atomicMin(p1, u1);
  }

  // ---------------- ticket: last block reduces + combines ----------------
  __threadfence();
  __syncthreads();
  if (t == 0)
    lastFlag = (atomicAdd((unsigned int*)(ws + 7), 1u) == (unsigned int)(NBLK - 1));
  __syncthreads();
  if (lastFlag) {
    __threadfence();  // acquire
    float ssum = 0.0f;
    const uint4* m4 = (const uint4*)minarr;
    for (int i = t; i < NB * NNODES / 4; i += 256) {
      const uint4 v = m4[i];
      ssum += sqrtf(fmaxf(__uint_as_float(v.x), 1e-12f));
      ssum += sqrtf(fmaxf(__uint_as_float(v.y), 1e-12f));
      ssum += sqrtf(fmaxf(__uint_as_float(v.z), 1e-12f));
      ssum += sqrtf(fmaxf(__uint_as_float(v.w), 1e-12f));
    }
    ssum = waveSum(ssum);
    __syncthreads();
    if (lane == 0) red[0][wave] = ssum;
    __syncthreads();
    if (t == 0) {
      const float surf_sum = red[0][0] + red[0][1] + red[0][2] + red[0][3];
      const float chf = ws[0] / (float)(KK * NB * PP);
      const float sep = ws[1] / (float)(NB * KK * PP * (PP - 1));
      const float surf = surf_sum / (float)(NB * NNODES);
      const float cov = ws[3] / (float)(NB * KK * 3);
      const float axis = 1.0f - ws[4] / (float)NB;
      const float loc = ws[5] / (float)NB;
      const float reg = ws[6] / (float)NCOEF;
      out[0] = chf + cov + surf * 5.0f + (loc + 0.5f * axis) + reg * 0.01f + sep * 2.0f;
    }
  }
}

extern "C" void kernel_launch(void* const* d_in, const int* in_sizes, int n_in,
                              void* d_out, int out_size, void* d_ws, size_t ws_size,
                              hipStream_t stream) {
  const float* coefs = (const float*)d_in[0];
  const float* preds = (const float*)d_in[1];
  const float* nodes = (const float*)d_in[2];
  const float* cloud = (const float*)d_in[3];
  const int* cls = (const int*)d_in[4];
  const float* pjl = (const float*)d_in[5];
  const float* pja = (const float*)d_in[6];
  const float* gjl = (const float*)d_in[7];
  const float* gja = (const float*)d_in[8];
  const float* gps = (const float*)d_in[9];
  float* out = (float*)d_out;
  float* ws = (float*)d_ws;
  unsigned int* minarr = (unsigned int*)(ws + 8);

  hipMemsetAsync(ws, 0, 8 * sizeof(float), stream);
  hipMemsetAsync(minarr, 0xFF, NB * NNODES * sizeof(unsigned int), stream);
  mega_kernel<<<NBLK, 256, 0, stream>>>(coefs, preds, nodes, cloud, cls,
                                        pjl, pja, gjl, gja, gps, ws, minarr, out);
}

// Round 5
// 80.345 us; speedup vs baseline: 1.3647x; 1.3072x over previous
//
#include <hip/hip_runtime.h>
#include <math.h>

#define NB 32
#define KK 2
#define PP 256
#define NCLOUD 8192
#define NNODES 512   // K*P
#define NCOEF 163840 // B*K*P*COEF_D
#define SURF0 193
#define NSURF 256                 // 32 b x 8 super-chunks of 1024 pts
#define NBLK (SURF0 + NSURF)      // 449
// minarr layout (uint d^2, init 0xFF): [0,16384) surf; [16384,32768) chfwd; [32768,49152) chbwd
#define MA_SURF 0
#define MA_FWD 16384
#define MA_BWD 32768
#define MA_TOT 49152

__device__ inline float waveSum(float v) {
#pragma unroll
  for (int o = 32; o > 0; o >>= 1) v += __shfl_down(v, o);
  return v;
}
__device__ inline float waveMax(float v) {
#pragma unroll
  for (int o = 32; o > 0; o >>= 1) v = fmaxf(v, __shfl_down(v, o));
  return v;
}
__device__ inline float waveMin(float v) {
#pragma unroll
  for (int o = 32; o > 0; o >>= 1) v = fminf(v, __shfl_down(v, o));
  return v;
}
__device__ inline float smooth_l1(float d) {
  d = fabsf(d);
  return d < 0.1f ? 5.0f * d * d : d - 0.05f;
}

// Grid layout:
//   [0,64)    chamfer+sep per (b,k); wave w owns j-quarter [64w,64w+64)
//   [64,128)  coverage per (b,k)
//   [128,192) regularizer
//   192       joint
//   [193,449) surf: s = bid-193, b = s>>3, super-chunk c = s&7 (1024 pts);
//             wave w owns pts [256w,256w+256), lane holds 8 nodes (lane+64q)
__global__ __launch_bounds__(256) void mega_kernel(
    const float* __restrict__ coefs,
    const float* __restrict__ preds,
    const float* __restrict__ nodes,
    const float* __restrict__ cloud,
    const int* __restrict__ cls,
    const float* __restrict__ pjl, const float* __restrict__ pja,
    const float* __restrict__ gjl, const float* __restrict__ gja,
    const float* __restrict__ gps,
    float* __restrict__ ws, unsigned int* __restrict__ minarr,
    float* __restrict__ out) {
  const int bid = blockIdx.x;
  const int t = threadIdx.x;
  const int wave = t >> 6, lane = t & 63;
  __shared__ float4 sh4[1024];   // 16 KB
  __shared__ float red[12][4];
  __shared__ int lastFlag;

  if (bid < 64) {
    // ---------------- chamfer + separation per (b,k) ----------------
    const int bk = bid;
    const float* pb = preds + (size_t)bk * PP * 3;
    const float* nbp = nodes + (size_t)bk * PP * 3;
    // wave stages its own j-quarter (wave-local; no cross-wave reads)
    const int j0 = wave * 64;
    {
      const int j = j0 + lane;
      float x = pb[3 * j], y = pb[3 * j + 1], z = pb[3 * j + 2];
      sh4[j] = make_float4(x, y, z, x * x + y * y + z * z);           // preds
      x = nbp[3 * j]; y = nbp[3 * j + 1]; z = nbp[3 * j + 2];
      sh4[256 + j] = make_float4(x, y, z, x * x + y * y + z * z);     // nodes
    }
    // lane's own 4 preds / 4 nodes from global (one-time)
    float4 ptv[4], ntv[4];
#pragma unroll
    for (int q = 0; q < 4; ++q) {
      const int n = lane + q * 64;
      float x = pb[3 * n], y = pb[3 * n + 1], z = pb[3 * n + 2];
      ptv[q] = make_float4(x, y, z, x * x + y * y + z * z);
      x = nbp[3 * n]; y = nbp[3 * n + 1]; z = nbp[3 * n + 2];
      ntv[q] = make_float4(x, y, z, x * x + y * y + z * z);
    }
    const float s0 = gps[bk * 3 + 0], s1 = gps[bk * 3 + 1], s2 = gps[bk * 3 + 2];
    const float thr = sqrtf(s0 * s0 + s1 * s1 + s2 * s2) * 0.125f;
    float g1[4], g2[4], sep = 0.0f;
#pragma unroll
    for (int q = 0; q < 4; ++q) { g1[q] = 1e30f; g2[q] = 1e30f; }
#pragma unroll 2
    for (int jj = 0; jj < 64; ++jj) {
      const float4 pj = sh4[j0 + jj];
      const float4 nj = sh4[256 + j0 + jj];
#pragma unroll
      for (int q = 0; q < 4; ++q) {
        float dot = fmaf(ptv[q].x, nj.x, fmaf(ptv[q].y, nj.y, ptv[q].z * nj.z));
        g1[q] = fminf(g1[q], fmaf(-2.0f, dot, nj.w));
        dot = fmaf(ntv[q].x, pj.x, fmaf(ntv[q].y, pj.y, ntv[q].z * pj.z));
        g2[q] = fminf(g2[q], fmaf(-2.0f, dot, pj.w));
        dot = fmaf(ntv[q].x, nj.x, fmaf(ntv[q].y, nj.y, ntv[q].z * nj.z));
        const float d2 = fmaf(-2.0f, dot, ntv[q].w + nj.w);
        const float d = sqrtf(fmaxf(d2, 0.0f));
        if (j0 + jj != lane + q * 64) sep += fmaxf(thr - d, 0.0f);
      }
    }
#pragma unroll
    for (int q = 0; q < 4; ++q) {
      const unsigned int uf =
          __float_as_uint(fmaxf(ptv[q].w + g1[q], 0.0f));
      const unsigned int ub =
          __float_as_uint(fmaxf(ntv[q].w + g2[q], 0.0f));
      unsigned int* pf = &minarr[MA_FWD + bk * PP + lane + q * 64];
      unsigned int* pbk = &minarr[MA_BWD + bk * PP + lane + q * 64];
      if (*pf > uf) atomicMin(pf, uf);
      if (*pbk > ub) atomicMin(pbk, ub);
    }
    sep = waveSum(sep);
    if (lane == 0) atomicAdd(&ws[1], sep);

  } else if (bid < 128) {
    // ---------------- coverage per (b,k) ----------------
    const int bk = bid - 64;
    const int b = bk >> 1;
    const int k = bk & 1;
    float pmax0 = -1e9f, pmax1 = -1e9f, pmax2 = -1e9f;
    float pmin0 = 1e9f, pmin1 = 1e9f, pmin2 = 1e9f;
    const float* cb = cloud + (size_t)b * NCLOUD * 3;
    const int* lb = cls + (size_t)b * NCLOUD;
    for (int i = t; i < NCLOUD; i += 256) {
      if (lb[i] == k) {
        const float x = cb[i * 3 + 0], y = cb[i * 3 + 1], z = cb[i * 3 + 2];
        pmax0 = fmaxf(pmax0, x); pmax1 = fmaxf(pmax1, y); pmax2 = fmaxf(pmax2, z);
        pmin0 = fminf(pmin0, x); pmin1 = fminf(pmin1, y); pmin2 = fminf(pmin2, z);
      }
    }
    const float* nb = nodes + (size_t)bk * PP * 3;
    const float kx = nb[t * 3 + 0], ky = nb[t * 3 + 1], kz = nb[t * 3 + 2];
    pmax0 = waveMax(pmax0); pmax1 = waveMax(pmax1); pmax2 = waveMax(pmax2);
    pmin0 = waveMin(pmin0); pmin1 = waveMin(pmin1); pmin2 = waveMin(pmin2);
    float kmax0 = waveMax(kx), kmax1 = waveMax(ky), kmax2 = waveMax(kz);
    float kmin0 = waveMin(kx), kmin1 = waveMin(ky), kmin2 = waveMin(kz);
    if (lane == 0) {
      red[0][wave] = pmax0; red[1][wave] = pmax1; red[2][wave] = pmax2;
      red[3][wave] = pmin0; red[4][wave] = pmin1; red[5][wave] = pmin2;
      red[6][wave] = kmax0; red[7][wave] = kmax1; red[8][wave] = kmax2;
      red[9][wave] = kmin0; red[10][wave] = kmin1; red[11][wave] = kmin2;
    }
    __syncthreads();
    if (t == 0) {
      float v[12];
#pragma unroll
      for (int q = 0; q < 12; ++q) {
        if (q < 3 || (q >= 6 && q < 9))
          v[q] = fmaxf(fmaxf(red[q][0], red[q][1]), fmaxf(red[q][2], red[q][3]));
        else
          v[q] = fminf(fminf(red[q][0], red[q][1]), fminf(red[q][2], red[q][3]));
      }
      float s = 0.0f;
#pragma unroll
      for (int c2 = 0; c2 < 3; ++c2)
        s += 0.5f * (smooth_l1(v[6 + c2] - v[0 + c2]) + smooth_l1(v[9 + c2] - v[3 + c2]));
      atomicAdd(&ws[3], s);
    }

  } else if (bid < 192) {
    // ---------------- regularizer ----------------
    const int r = bid - 128;
    const float4* c4 = (const float4*)coefs;
    float v = 0.0f;
    for (int i = r * 256 + t; i < NCOEF / 4; i += 64 * 256) {
      const float4 q = c4[i];
      v += q.x * q.x + q.y * q.y + q.z * q.z + q.w * q.w;
    }
    v = waveSum(v);
    if (lane == 0) red[0][wave] = v;
    __syncthreads();
    if (t == 0)
      atomicAdd(&ws[6], red[0][0] + red[0][1] + red[0][2] + red[0][3]);

  } else if (bid == 192) {
    // ---------------- joint ----------------
    float cosv = 0.0f, locv = 0.0f;
    if (t < NB) {
      const float axj = pja[t * 3 + 0], ayj = pja[t * 3 + 1], azj = pja[t * 3 + 2];
      const float gx = gja[t * 3 + 0], gy = gja[t * 3 + 1], gz = gja[t * 3 + 2];
      const float dot = axj * gx + ayj * gy + azj * gz;
      const float na = sqrtf(axj * axj + ayj * ayj + azj * azj);
      const float nbn = sqrtf(gx * gx + gy * gy + gz * gz);
      cosv = dot / fmaxf(na * nbn, 1e-8f);
      const float ux = gx / nbn, uy = gy / nbn, uz = gz / nbn;
      const float px = gjl[t * 3 + 0], py = gjl[t * 3 + 1], pz = gjl[t * 3 + 2];
      const float qx = px + ux, qy = py + uy, qz = pz + uz;
      const float rx = pjl[t * 3 + 0], ry = pjl[t * 3 + 1], rz = pjl[t * 3 + 2];
      const float xx = px - qx, xy = py - qy, xz = pz - qz;
      const float tnum = (rx - qx) * xx + (ry - qy) * xy + (rz - qz) * xz;
      const float tden = xx * xx + xy * xy + xz * xz;
      const float tv = tnum / tden;
      const float vx = tv * xx + (qx - rx);
      const float vy = tv * xy + (qy - ry);
      const float vz = tv * xz + (qz - rz);
      locv = sqrtf(vx * vx + vy * vy + vz * vz);
    }
    cosv = waveSum(cosv);
    locv = waveSum(locv);
    if (t == 0) { atomicAdd(&ws[4], cosv); atomicAdd(&ws[5], locv); }

  } else {
    // ---------------- surface loss partial: (b, 1024-pt super-chunk) ----------------
    const int s = bid - SURF0;
    const int b = s >> 3;
    const int c = s & 7;
    const float* cb = cloud + ((size_t)b * NCLOUD + (size_t)c * 1024) * 3;
#pragma unroll
    for (int g = 0; g < 4; ++g) {
      const int idx = g * 256 + t;
      const float qx = cb[3 * idx], qy = cb[3 * idx + 1], qz = cb[3 * idx + 2];
      sh4[idx] = make_float4(qx, qy, qz, 0.5f * (qx * qx + qy * qy + qz * qz));
    }
    __syncthreads();
    const float* nb = nodes + (size_t)b * NNODES * 3;
    float nxv[8], nyv[8], nzv[8], nnv[8], mg[8];
#pragma unroll
    for (int q = 0; q < 8; ++q) {
      const int n = lane + q * 64;
      nxv[q] = nb[3 * n]; nyv[q] = nb[3 * n + 1]; nzv[q] = nb[3 * n + 2];
      nnv[q] = nxv[q] * nxv[q] + nyv[q] * nyv[q] + nzv[q] * nzv[q];
      mg[q] = 1e30f;
    }
    const int p0 = wave * 256;
#pragma unroll 2
    for (int j = 0; j < 256; ++j) {
      const float4 q4 = sh4[p0 + j];
#pragma unroll
      for (int q = 0; q < 8; ++q)
        mg[q] = fminf(mg[q],
                      fmaf(-nxv[q], q4.x,
                           fmaf(-nyv[q], q4.y, fmaf(-nzv[q], q4.z, q4.w))));
    }
#pragma unroll
    for (int q = 0; q < 8; ++q) {
      const unsigned int u =
          __float_as_uint(fmaxf(2.0f * mg[q] + nnv[q], 0.0f));
      unsigned int* p = &minarr[MA_SURF + b * NNODES + lane + q * 64];
      if (*p > u) atomicMin(p, u);   // stale read >= current: skip is safe
    }
  }

  // ---------------- ticket: last block reduces + combines ----------------
  __threadfence();
  __syncthreads();
  if (t == 0)
    lastFlag = (atomicAdd((unsigned int*)(ws + 7), 1u) == (unsigned int)(NBLK - 1));
  __syncthreads();
  if (lastFlag) {
    __threadfence();  // acquire
    float ssum = 0.0f, csum = 0.0f;
    const uint4* m4 = (const uint4*)minarr;
    for (int i = t; i < MA_TOT / 4; i += 256) {
      const uint4 v = m4[i];
      float sgroup = sqrtf(fmaxf(__uint_as_float(v.x), 1e-12f)) +
                     sqrtf(fmaxf(__uint_as_float(v.y), 1e-12f)) +
                     sqrtf(fmaxf(__uint_as_float(v.z), 1e-12f)) +
                     sqrtf(fmaxf(__uint_as_float(v.w), 1e-12f));
      if (i < MA_FWD / 4) ssum += sgroup; else csum += sgroup;
    }
    ssum = waveSum(ssum);
    csum = waveSum(csum);
    __syncthreads();
    if (lane == 0) { red[0][wave] = ssum; red[1][wave] = csum; }
    __syncthreads();
    if (t == 0) {
      const float surf_sum = red[0][0] + red[0][1] + red[0][2] + red[0][3];
      const float chf_sum = red[1][0] + red[1][1] + red[1][2] + red[1][3];
      const float chf = chf_sum / (float)(KK * NB * PP);
      const float sep = ws[1] / (float)(NB * KK * PP * (PP - 1));
      const float surf = surf_sum / (float)(NB * NNODES);
      const float cov = ws[3] / (float)(NB * KK * 3);
      const float axis = 1.0f - ws[4] / (float)NB;
      const float loc = ws[5] / (float)NB;
      const float reg = ws[6] / (float)NCOEF;
      out[0] = chf + cov + surf * 5.0f + (loc + 0.5f * axis) + reg * 0.01f + sep * 2.0f;
    }
  }
}

extern "C" void kernel_launch(void* const* d_in, const int* in_sizes, int n_in,
                              void* d_out, int out_size, void* d_ws, size_t ws_size,
                              hipStream_t stream) {
  const float* coefs = (const float*)d_in[0];
  const float* preds = (const float*)d_in[1];
  const float* nodes = (const float*)d_in[2];
  const float* cloud = (const float*)d_in[3];
  const int* cls = (const int*)d_in[4];
  const float* pjl = (const float*)d_in[5];
  const float* pja = (const float*)d_in[6];
  const float* gjl = (const float*)d_in[7];
  const float* gja = (const float*)d_in[8];
  const float* gps = (const float*)d_in[9];
  float* out = (float*)d_out;
  float* ws = (float*)d_ws;
  unsigned int* minarr = (unsigned int*)(ws + 8);

  hipMemsetAsync(ws, 0, 8 * sizeof(float), stream);
  hipMemsetAsync(minarr, 0xFF, MA_TOT * sizeof(unsigned int), stream);
  mega_kernel<<<NBLK, 256, 0, stream>>>(coefs, preds, nodes, cloud, cls,
                                        pjl, pja, gjl, gja, gps, ws, minarr, out);
}